// Round 1
// baseline (1231.192 us; speedup 1.0000x reference)
//
#include <hip/hip_runtime.h>
#include <math.h>

#define NWF    307
#define NWTOT  614
#define MROWS  39296   // NWTOT * 64

typedef float f32x4 __attribute__((ext_vector_type(4)));
typedef short s16x8 __attribute__((ext_vector_type(8)));

__device__ __forceinline__ short f2bf(float f) {
  unsigned int u = __builtin_bit_cast(unsigned int, f);
  u += 0x7fffu + ((u >> 16) & 1u);
  return (short)(u >> 16);
}

__device__ __forceinline__ f32x4 mfma16(s16x8 a, s16x8 b, f32x4 c) {
  return __builtin_amdgcn_mfma_f32_16x16x32_bf16(a, b, c, 0, 0, 0);
}

// ---------------- window scores: mean of 64 uncertainty values ----------------
__global__ __launch_bounds__(64) void score_k(const float* __restrict__ unc,
                                              float* __restrict__ scores) {
  int blk = blockIdx.x;              // 0..2047 = b*1024 + win
  int b = blk >> 10, t = blk & 1023;
  int ty = t >> 5, tx = t & 31;
  int lane = threadIdx.x;
  float v = unc[(size_t)b * 65536 + (size_t)(ty * 8 + (lane >> 3)) * 256 + tx * 8 + (lane & 7)];
  for (int m = 32; m; m >>= 1) v += __shfl_xor(v, m);
  if (lane == 0) scores[blk] = v * (1.0f / 64.0f);
}

// ---------------- exact top-k via rank counting (per batch) ----------------
__global__ __launch_bounds__(1024) void topk_k(const float* __restrict__ scores,
                                               int* __restrict__ selidx) {
  __shared__ float sc[1024];
  int b = blockIdx.x, t = threadIdx.x;
  float s = scores[b * 1024 + t];
  sc[t] = s;
  __syncthreads();
  int rank = 0;
  for (int j = 0; j < 1024; ++j) {
    float o = sc[j];
    rank += (o > s) || (o == s && j < t);
  }
  if (rank < NWF) selidx[b * NWF + rank] = t;
}

// ---------------- gather selected windows: wf[slot][tok][c] ----------------
__global__ __launch_bounds__(256) void gather_k(const float* __restrict__ fm,
                                                const int* __restrict__ selidx,
                                                float* __restrict__ wf) {
  __shared__ float tile[64][33];
  int slot = blockIdx.x;
  int b = slot >= NWF;
  int w = selidx[slot];
  int y0 = (w >> 5) * 8, x0 = (w & 31) * 8;
  int tid = threadIdx.x;
  int j = tid & 7, i = (tid >> 3) & 7, c4 = tid >> 6;   // read mapping
  int cc2 = tid & 31, t4 = tid >> 5;                    // write mapping
  for (int c0 = 0; c0 < 256; c0 += 32) {
    for (int cs = 0; cs < 8; ++cs) {
      int c = c0 + cs * 4 + c4;
      tile[i * 8 + j][cs * 4 + c4] =
          fm[((size_t)(b * 256 + c) * 256 + y0 + i) * 256 + x0 + j];
    }
    __syncthreads();
    for (int ts = 0; ts < 8; ++ts) {
      int tok = ts * 8 + t4;
      wf[(size_t)(slot * 64 + tok) * 256 + c0 + cc2] = tile[tok][cc2];
    }
    __syncthreads();
  }
}

// ---------------- out = feature_map (identity part of un-windowize) ----------------
__global__ void copy_k(const f32x4* __restrict__ in, f32x4* __restrict__ out, int n4) {
  int i = blockIdx.x * blockDim.x + threadIdx.x;
  int stride = gridDim.x * blockDim.x;
  for (; i < n4; i += stride) out[i] = in[i];
}

// ---------------- depthwise 8x8/8 conv + LayerNorm + exact GELU ----------------
__global__ __launch_bounds__(256) void convlg_k(const float* __restrict__ fm,
                                                const float* __restrict__ srw,
                                                const float* __restrict__ srb,
                                                const float* __restrict__ lng,
                                                const float* __restrict__ lnb,
                                                float* __restrict__ g) {
  int blk = blockIdx.x;              // 0..2047 = b*1024 + token
  int b = blk >> 10, t = blk & 1023;
  int ty = t >> 5, tx = t & 31;
  int c = threadIdx.x;
  int lane = threadIdx.x & 63, wv = threadIdx.x >> 6;
  const float* fp = fm + ((size_t)(b * 256 + c) * 256 + ty * 8) * 256 + tx * 8;
  const float* wp = srw + c * 64;
  float s = 0.f;
#pragma unroll
  for (int i = 0; i < 8; ++i) {
    f32x4 r0 = *(const f32x4*)(fp + (size_t)i * 256);
    f32x4 r1 = *(const f32x4*)(fp + (size_t)i * 256 + 4);
    f32x4 w0 = *(const f32x4*)(wp + i * 8);
    f32x4 w1 = *(const f32x4*)(wp + i * 8 + 4);
    s += r0[0] * w0[0] + r0[1] * w0[1] + r0[2] * w0[2] + r0[3] * w0[3];
    s += r1[0] * w1[0] + r1[1] * w1[1] + r1[2] * w1[2] + r1[3] * w1[3];
  }
  s += srb[c];
  // LayerNorm across 256 channels (one block)
  float sum = s, sq = s * s;
  for (int m = 32; m; m >>= 1) { sum += __shfl_xor(sum, m); sq += __shfl_xor(sq, m); }
  __shared__ float red[8];
  if (lane == 0) { red[wv] = sum; red[4 + wv] = sq; }
  __syncthreads();
  sum = red[0] + red[1] + red[2] + red[3];
  sq  = red[4] + red[5] + red[6] + red[7];
  float mu  = sum * (1.f / 256.f);
  float var = sq * (1.f / 256.f) - mu * mu;
  float xn = (s - mu) * rsqrtf(var + 1e-5f);
  float y = xn * lng[c] + lnb[c];
  float ge = 0.5f * y * (1.f + erff(y * 0.70710678118654752f));
  g[(size_t)(b * 1024 + t) * 256 + c] = ge;
}

// ---------------- weight transpose + bf16 cast: Wt[n][k] = bf16(W[k][n]) ----------------
__global__ __launch_bounds__(256) void wtrans_k(const float* __restrict__ W,
                                                short* __restrict__ Wt, int N) {
  int n = blockIdx.x, k = threadIdx.x;
  Wt[(size_t)n * 256 + k] = f2bf(W[(size_t)k * N + n]);
}

// ---------------- GEMM: Y[M,N] = X[M,256] @ W[256,N], MFMA bf16 ----------------
// EPI 0: store bf16 [row][col]   (q buffers)
// EPI 1: cols<256 -> k bf16 [row][col]; cols>=256 -> vT[( (row>>kvshift)*4+h )*64+ch][tok]
// EPI 2: fp32 [row][col] = acc + bias[col]   (projection)
template <int N, int EPI>
__global__ __launch_bounds__(256) void gemm_k(const float* __restrict__ X,
                                              const short* __restrict__ Wt,
                                              const float* __restrict__ bias,
                                              short* __restrict__ outb,
                                              short* __restrict__ outvT,
                                              float* __restrict__ outf,
                                              int kvshift) {
  const int lane = threadIdx.x & 63;
  const int wv = threadIdx.x >> 6;
  const int l16 = lane & 15, quad = lane >> 4;
  const int row0 = blockIdx.x * 64 + wv * 16;
  constexpr int NT = N / 16;
  f32x4 acc[NT];
#pragma unroll
  for (int i = 0; i < NT; ++i) { acc[i][0] = 0.f; acc[i][1] = 0.f; acc[i][2] = 0.f; acc[i][3] = 0.f; }
  const float* xrow = X + (size_t)(row0 + l16) * 256 + quad * 8;
  const short* wbase = Wt + (size_t)l16 * 256 + quad * 8;
#pragma unroll
  for (int ks = 0; ks < 8; ++ks) {
    f32x4 xa = *(const f32x4*)(xrow + ks * 32);
    f32x4 xb = *(const f32x4*)(xrow + ks * 32 + 4);
    s16x8 a;
    a[0] = f2bf(xa[0]); a[1] = f2bf(xa[1]); a[2] = f2bf(xa[2]); a[3] = f2bf(xa[3]);
    a[4] = f2bf(xb[0]); a[5] = f2bf(xb[1]); a[6] = f2bf(xb[2]); a[7] = f2bf(xb[3]);
#pragma unroll
    for (int nt = 0; nt < NT; ++nt) {
      s16x8 b = *(const s16x8*)(wbase + (size_t)nt * 16 * 256 + ks * 32);
      acc[nt] = mfma16(a, b, acc[nt]);
    }
  }
#pragma unroll
  for (int nt = 0; nt < NT; ++nt) {
#pragma unroll
    for (int r = 0; r < 4; ++r) {
      int col = nt * 16 + l16;
      int row = row0 + quad * 4 + r;
      float v = acc[nt][r];
      if (EPI == 0) {
        outb[(size_t)row * 256 + col] = f2bf(v);
      } else if (EPI == 1) {
        if (col < 256) {
          outb[(size_t)row * 256 + col] = f2bf(v);
        } else {
          int c2 = col - 256, hh = c2 >> 6, ch = c2 & 63;
          int grp = row >> kvshift, tok = row & ((1 << kvshift) - 1);
          outvT[((size_t)((grp * 4 + hh) * 64 + ch) << kvshift) + tok] = f2bf(v);
        }
      } else {
        outf[(size_t)row * 256 + col] = v + bias[col];
      }
    }
  }
}

// ---------------- flash attention: block=window, wave=head; wf += softmax(QK^T*s)V ----------------
__global__ __launch_bounds__(256) void attn_k(const short* __restrict__ qbuf,
                                              const short* __restrict__ kbuf,
                                              const short* __restrict__ vT,
                                              float* __restrict__ wf, int kvlen) {
  __shared__ short Plds[4][64][72];
  const int lane = threadIdx.x & 63;
  const int h = threadIdx.x >> 6;
  const int l16 = lane & 15, quad = lane >> 4;
  const int w = blockIdx.x;
  const int qrow0 = w * 64;
  const int grp = (kvlen == 64) ? w : (w >= NWF ? 1 : 0);
  const size_t krow0 = (size_t)grp * kvlen;
  const short* vTb = vT + (size_t)(grp * 4 + h) * 64 * kvlen;
  const float LOG2E = 1.4426950408889634f;
  const float SC = 0.125f;

  s16x8 aq[4][2];
#pragma unroll
  for (int mt = 0; mt < 4; ++mt)
#pragma unroll
    for (int ks = 0; ks < 2; ++ks)
      aq[mt][ks] = *(const s16x8*)(qbuf + (size_t)(qrow0 + mt * 16 + l16) * 256 + h * 64 + ks * 32 + quad * 8);

  f32x4 O[4][4], m_i[4], l_i[4];
#pragma unroll
  for (int mt = 0; mt < 4; ++mt) {
#pragma unroll
    for (int r = 0; r < 4; ++r) { m_i[mt][r] = -1e30f; l_i[mt][r] = 0.f; }
#pragma unroll
    for (int nt = 0; nt < 4; ++nt)
#pragma unroll
      for (int r = 0; r < 4; ++r) O[mt][nt][r] = 0.f;
  }

  const int ntile = kvlen >> 6;
  for (int t = 0; t < ntile; ++t) {
    f32x4 S[4][4];
#pragma unroll
    for (int mt = 0; mt < 4; ++mt)
#pragma unroll
      for (int nt = 0; nt < 4; ++nt)
#pragma unroll
        for (int r = 0; r < 4; ++r) S[mt][nt][r] = 0.f;

#pragma unroll
    for (int ks = 0; ks < 2; ++ks)
#pragma unroll
      for (int nt = 0; nt < 4; ++nt) {
        s16x8 bk = *(const s16x8*)(kbuf + (krow0 + t * 64 + nt * 16 + l16) * 256 + h * 64 + ks * 32 + quad * 8);
#pragma unroll
        for (int mt = 0; mt < 4; ++mt) S[mt][nt] = mfma16(aq[mt][ks], bk, S[mt][nt]);
      }

#pragma unroll
    for (int mt = 0; mt < 4; ++mt) {
      f32x4 mx;
#pragma unroll
      for (int r = 0; r < 4; ++r)
        mx[r] = fmaxf(fmaxf(S[mt][0][r], S[mt][1][r]), fmaxf(S[mt][2][r], S[mt][3][r])) * SC;
#pragma unroll
      for (int msk = 1; msk <= 8; msk <<= 1)
#pragma unroll
        for (int r = 0; r < 4; ++r) {
          float v = mx[r];
          mx[r] = fmaxf(v, __shfl_xor(v, msk));
        }
      f32x4 mn, al;
#pragma unroll
      for (int r = 0; r < 4; ++r) {
        mn[r] = fmaxf(m_i[mt][r], mx[r]);
        al[r] = __builtin_amdgcn_exp2f((m_i[mt][r] - mn[r]) * LOG2E);
        m_i[mt][r] = mn[r];
      }
      f32x4 rs;
#pragma unroll
      for (int r = 0; r < 4; ++r) rs[r] = 0.f;
#pragma unroll
      for (int nt = 0; nt < 4; ++nt)
#pragma unroll
        for (int r = 0; r < 4; ++r) {
          float p = __builtin_amdgcn_exp2f((S[mt][nt][r] * SC - mn[r]) * LOG2E);
          S[mt][nt][r] = p;
          rs[r] += p;
          O[mt][nt][r] *= al[r];
        }
#pragma unroll
      for (int msk = 1; msk <= 8; msk <<= 1)
#pragma unroll
        for (int r = 0; r < 4; ++r) {
          float v = rs[r];
          rs[r] = v + __shfl_xor(v, msk);
        }
#pragma unroll
      for (int r = 0; r < 4; ++r) l_i[mt][r] = l_i[mt][r] * al[r] + rs[r];
    }

    // P: C/D layout -> LDS -> A layout (per-wave region)
#pragma unroll
    for (int mt = 0; mt < 4; ++mt)
#pragma unroll
      for (int nt = 0; nt < 4; ++nt)
#pragma unroll
        for (int r = 0; r < 4; ++r)
          Plds[h][mt * 16 + quad * 4 + r][nt * 16 + l16] = f2bf(S[mt][nt][r]);
    __syncthreads();

#pragma unroll
    for (int ks2 = 0; ks2 < 2; ++ks2) {
      s16x8 ap[4];
#pragma unroll
      for (int mt = 0; mt < 4; ++mt)
        ap[mt] = *(const s16x8*)&Plds[h][mt * 16 + l16][ks2 * 32 + quad * 8];
#pragma unroll
      for (int nt = 0; nt < 4; ++nt) {
        s16x8 bv = *(const s16x8*)(vTb + (size_t)(nt * 16 + l16) * kvlen + t * 64 + ks2 * 32 + quad * 8);
#pragma unroll
        for (int mt = 0; mt < 4; ++mt) O[mt][nt] = mfma16(ap[mt], bv, O[mt][nt]);
      }
    }
    __syncthreads();
  }

#pragma unroll
  for (int mt = 0; mt < 4; ++mt)
#pragma unroll
    for (int nt = 0; nt < 4; ++nt)
#pragma unroll
      for (int r = 0; r < 4; ++r) {
        size_t oi = (size_t)(qrow0 + mt * 16 + quad * 4 + r) * 256 + h * 64 + nt * 16 + l16;
        wf[oi] += O[mt][nt][r] / l_i[mt][r];
      }
}

// ---------------- scatter-add projected windows into out ----------------
__global__ __launch_bounds__(256) void scatter_k(const float* __restrict__ proj,
                                                 const int* __restrict__ selidx,
                                                 float* __restrict__ out) {
  int slot = blockIdx.x;
  int b = slot >= NWF;
  int w = selidx[slot];
  int y0 = (w >> 5) * 8, x0 = (w & 31) * 8;
  int tid = threadIdx.x;
  int j = tid & 7, c8 = tid >> 3;   // c8 in 0..31
#pragma unroll
  for (int i = 0; i < 8; ++i)
    for (int cb = 0; cb < 8; ++cb) {
      int c = cb * 32 + c8;
      size_t oidx = ((size_t)(b * 256 + c) * 256 + y0 + i) * 256 + x0 + j;
      out[oidx] += proj[(size_t)(slot * 64 + i * 8 + j) * 256 + c];
    }
}

extern "C" void kernel_launch(void* const* d_in, const int* in_sizes, int n_in,
                              void* d_out, int out_size, void* d_ws, size_t ws_size,
                              hipStream_t stream) {
  const float* fm    = (const float*)d_in[0];
  const float* unc   = (const float*)d_in[1];
  const float* srw   = (const float*)d_in[2];
  const float* srb   = (const float*)d_in[3];
  const float* lng   = (const float*)d_in[4];
  const float* lnb   = (const float*)d_in[5];
  const float* wq_l  = (const float*)d_in[6];
  const float* wkv_l = (const float*)d_in[7];
  const float* wq_g  = (const float*)d_in[8];
  const float* wkv_g = (const float*)d_in[9];
  const float* wpm   = (const float*)d_in[10];
  const float* bp    = (const float*)d_in[11];
  float* out = (float*)d_out;

  char* ws = (char*)d_ws;
  size_t off = 0;
  auto alloc = [&](size_t bytes) -> char* {
    char* p = ws + off;
    off += (bytes + 255) & ~(size_t)255;
    return p;
  };
  float* wf     = (float*)alloc((size_t)MROWS * 256 * 4);   // 40.24 MB
  short* qbuf   = (short*)alloc((size_t)MROWS * 256 * 2);   // 20.12 MB
  short* kbufl  = (short*)alloc((size_t)MROWS * 256 * 2);   // 20.12 MB (contiguous w/ qbuf)
  short* vTl    = (short*)alloc((size_t)MROWS * 256 * 2);   // 20.12 MB
  short* kbufg  = (short*)alloc((size_t)2048 * 256 * 2);
  short* vTg    = (short*)alloc((size_t)2048 * 256 * 2);
  float* g      = (float*)alloc((size_t)2048 * 256 * 4);
  float* scores = (float*)alloc(2048 * 4);
  int*   selidx = (int*)alloc(NWTOT * 4);
  short* wtql   = (short*)alloc(256 * 256 * 2);
  short* wtkvl  = (short*)alloc(512 * 256 * 2);
  short* wtqg   = (short*)alloc(256 * 256 * 2);
  short* wtkvg  = (short*)alloc(512 * 256 * 2);
  short* wtp    = (short*)alloc(256 * 256 * 2);
  float* proj   = (float*)qbuf;   // aliases qbuf+kbufl (both dead by projection time)

  // weights -> bf16 transposed
  wtrans_k<<<256, 256, 0, stream>>>(wq_l, wtql, 256);
  wtrans_k<<<512, 256, 0, stream>>>(wkv_l, wtkvl, 512);
  wtrans_k<<<256, 256, 0, stream>>>(wq_g, wtqg, 256);
  wtrans_k<<<512, 256, 0, stream>>>(wkv_g, wtkvg, 512);
  wtrans_k<<<256, 256, 0, stream>>>(wpm, wtp, 256);

  // selection
  score_k<<<2048, 64, 0, stream>>>(unc, scores);
  topk_k<<<2, 1024, 0, stream>>>(scores, selidx);
  gather_k<<<NWTOT, 256, 0, stream>>>(fm, selidx, wf);

  // independent: identity copy + global branch
  copy_k<<<8192, 256, 0, stream>>>((const f32x4*)fm, (f32x4*)out, 8388608);
  convlg_k<<<2048, 256, 0, stream>>>(fm, srw, srb, lng, lnb, g);

  // local window attention
  gemm_k<256, 0><<<MROWS / 64, 256, 0, stream>>>(wf, wtql, nullptr, qbuf, nullptr, nullptr, 0);
  gemm_k<512, 1><<<MROWS / 64, 256, 0, stream>>>(wf, wtkvl, nullptr, kbufl, vTl, nullptr, 6);
  attn_k<<<NWTOT, 256, 0, stream>>>(qbuf, kbufl, vTl, wf, 64);

  // global cross attention
  gemm_k<256, 0><<<MROWS / 64, 256, 0, stream>>>(wf, wtqg, nullptr, qbuf, nullptr, nullptr, 0);
  gemm_k<512, 1><<<2048 / 64, 256, 0, stream>>>(g, wtkvg, nullptr, kbufg, vTg, nullptr, 10);
  attn_k<<<NWTOT, 256, 0, stream>>>(qbuf, kbufg, vTg, wf, 1024);

  // projection + scatter-add
  gemm_k<256, 2><<<MROWS / 64, 256, 0, stream>>>(wf, wtp, bp, nullptr, nullptr, proj, 0);
  scatter_k<<<NWTOT, 256, 0, stream>>>(proj, selidx, out);
}

// Round 2
// 1131.421 us; speedup vs baseline: 1.0882x; 1.0882x over previous
//
#include <hip/hip_runtime.h>
#include <math.h>

#define NWF    307
#define NWTOT  614
#define MROWS  39296   // NWTOT * 64

typedef float f32x4 __attribute__((ext_vector_type(4)));
typedef short s16x8 __attribute__((ext_vector_type(8)));

__device__ __forceinline__ short f2bf(float f) {
  unsigned int u = __builtin_bit_cast(unsigned int, f);
  u += 0x7fffu + ((u >> 16) & 1u);
  return (short)(u >> 16);
}

__device__ __forceinline__ f32x4 mfma16(s16x8 a, s16x8 b, f32x4 c) {
  return __builtin_amdgcn_mfma_f32_16x16x32_bf16(a, b, c, 0, 0, 0);
}

// ---------------- window scores: mean of 64 uncertainty values ----------------
__global__ __launch_bounds__(64) void score_k(const float* __restrict__ unc,
                                              float* __restrict__ scores) {
  int blk = blockIdx.x;              // 0..2047 = b*1024 + win
  int b = blk >> 10, t = blk & 1023;
  int ty = t >> 5, tx = t & 31;
  int lane = threadIdx.x;
  float v = unc[(size_t)b * 65536 + (size_t)(ty * 8 + (lane >> 3)) * 256 + tx * 8 + (lane & 7)];
  for (int m = 32; m; m >>= 1) v += __shfl_xor(v, m);
  if (lane == 0) scores[blk] = v * (1.0f / 64.0f);
}

// ---------------- exact top-k via rank counting (per batch) ----------------
__global__ __launch_bounds__(1024) void topk_k(const float* __restrict__ scores,
                                               int* __restrict__ selidx) {
  __shared__ float sc[1024];
  int b = blockIdx.x, t = threadIdx.x;
  float s = scores[b * 1024 + t];
  sc[t] = s;
  __syncthreads();
  int rank = 0;
  for (int j = 0; j < 1024; ++j) {
    float o = sc[j];
    rank += (o > s) || (o == s && j < t);
  }
  if (rank < NWF) selidx[b * NWF + rank] = t;
}

// ---------------- gather selected windows: wf[slot][tok][c] ----------------
__global__ __launch_bounds__(256) void gather_k(const float* __restrict__ fm,
                                                const int* __restrict__ selidx,
                                                float* __restrict__ wf) {
  __shared__ float tile[64][33];
  int slot = blockIdx.x;
  int b = slot >= NWF;
  int w = selidx[slot];
  int y0 = (w >> 5) * 8, x0 = (w & 31) * 8;
  int tid = threadIdx.x;
  int j = tid & 7, i = (tid >> 3) & 7, c4 = tid >> 6;   // read mapping
  int cc2 = tid & 31, t4 = tid >> 5;                    // write mapping
  for (int c0 = 0; c0 < 256; c0 += 32) {
    for (int cs = 0; cs < 8; ++cs) {
      int c = c0 + cs * 4 + c4;
      tile[i * 8 + j][cs * 4 + c4] =
          fm[((size_t)(b * 256 + c) * 256 + y0 + i) * 256 + x0 + j];
    }
    __syncthreads();
    for (int ts = 0; ts < 8; ++ts) {
      int tok = ts * 8 + t4;
      wf[(size_t)(slot * 64 + tok) * 256 + c0 + cc2] = tile[tok][cc2];
    }
    __syncthreads();
  }
}

// ------- fused: out=fm copy + depthwise 8x8/8 conv + LayerNorm + exact GELU -------
// grid: 512 blocks = b(2) * ty(32) * txg(8); thread = channel; 4 tokens per block
__global__ __launch_bounds__(256) void convcopy_k(const float* __restrict__ fm,
                                                  const float* __restrict__ srw,
                                                  const float* __restrict__ srb,
                                                  const float* __restrict__ lng,
                                                  const float* __restrict__ lnb,
                                                  float* __restrict__ g,
                                                  float* __restrict__ out) {
  int blk = blockIdx.x;
  int b = blk >> 8, rr = blk & 255, ty = rr >> 3, txg = rr & 7;
  int c = threadIdx.x;
  int lane = c & 63, wv = c >> 6;
  size_t base = ((size_t)(b * 256 + c) * 256 + ty * 8) * 256 + txg * 32;
  const float* fp = fm + base;
  float* op = out + base;
  const float* wp = srw + c * 64;
  float acc[4] = {0.f, 0.f, 0.f, 0.f};
#pragma unroll
  for (int i = 0; i < 8; ++i) {
    f32x4 r[8];
#pragma unroll
    for (int u = 0; u < 8; ++u) r[u] = *(const f32x4*)(fp + (size_t)i * 256 + u * 4);
#pragma unroll
    for (int u = 0; u < 8; ++u) *(f32x4*)(op + (size_t)i * 256 + u * 4) = r[u];
    f32x4 w0 = *(const f32x4*)(wp + i * 8);
    f32x4 w1 = *(const f32x4*)(wp + i * 8 + 4);
#pragma unroll
    for (int t = 0; t < 4; ++t) {
      f32x4 ra = r[2 * t], rb = r[2 * t + 1];
      acc[t] += ra[0] * w0[0] + ra[1] * w0[1] + ra[2] * w0[2] + ra[3] * w0[3]
              + rb[0] * w1[0] + rb[1] * w1[1] + rb[2] * w1[2] + rb[3] * w1[3];
    }
  }
  float sb = srb[c];
#pragma unroll
  for (int t = 0; t < 4; ++t) acc[t] += sb;
  __shared__ float red[4][8];
#pragma unroll
  for (int t = 0; t < 4; ++t) {
    float s = acc[t], q = acc[t] * acc[t];
    for (int m = 32; m; m >>= 1) { s += __shfl_xor(s, m); q += __shfl_xor(q, m); }
    if (lane == 0) { red[t][wv] = s; red[t][4 + wv] = q; }
  }
  __syncthreads();
  float gc = lng[c], bc = lnb[c];
#pragma unroll
  for (int t = 0; t < 4; ++t) {
    float sum = red[t][0] + red[t][1] + red[t][2] + red[t][3];
    float sq  = red[t][4] + red[t][5] + red[t][6] + red[t][7];
    float mu  = sum * (1.f / 256.f);
    float var = sq * (1.f / 256.f) - mu * mu;
    float xn = (acc[t] - mu) * rsqrtf(var + 1e-5f);
    float y = xn * gc + bc;
    float ge = 0.5f * y * (1.f + erff(y * 0.70710678118654752f));
    g[(size_t)(b * 1024 + ty * 32 + txg * 4 + t) * 256 + c] = ge;
  }
}

// ---------------- weight transpose + bf16 cast: Wt[n][k] = bf16(W[k][n]) ----------------
__global__ __launch_bounds__(256) void wtrans_k(const float* __restrict__ W,
                                                short* __restrict__ Wt, int N) {
  int n = blockIdx.x, k = threadIdx.x;
  Wt[(size_t)n * 256 + k] = f2bf(W[(size_t)k * N + n]);
}

// ---------------- GEMM: Y = X[M,256] @ W[256,N]; wave = 16 rows x 128 cols ----------------
// grid: (M/64, N/128). EPI 0: bf16 [row][col]. EPI 1: col<256 -> kbuf bf16; else vT.
// EPI 2: fp32 [row][col] = acc + bias[col].
template <int EPI>
__global__ __launch_bounds__(256) void gemm_k(const float* __restrict__ X,
                                              const short* __restrict__ Wt,
                                              const float* __restrict__ bias,
                                              short* __restrict__ outb,
                                              short* __restrict__ outvT,
                                              float* __restrict__ outf,
                                              int kvshift) {
  const int lane = threadIdx.x & 63;
  const int wv = threadIdx.x >> 6;
  const int l16 = lane & 15, quad = lane >> 4;
  const int row0 = blockIdx.x * 64 + wv * 16;
  const int col0 = blockIdx.y * 128;
  f32x4 acc[8];
#pragma unroll
  for (int i = 0; i < 8; ++i) { acc[i][0] = 0.f; acc[i][1] = 0.f; acc[i][2] = 0.f; acc[i][3] = 0.f; }
  const float* xrow = X + (size_t)(row0 + l16) * 256 + quad * 8;
  const short* wbase = Wt + (size_t)(col0 + l16) * 256 + quad * 8;
#pragma unroll
  for (int ks = 0; ks < 8; ++ks) {
    f32x4 xa = *(const f32x4*)(xrow + ks * 32);
    f32x4 xb = *(const f32x4*)(xrow + ks * 32 + 4);
    s16x8 a;
    a[0] = f2bf(xa[0]); a[1] = f2bf(xa[1]); a[2] = f2bf(xa[2]); a[3] = f2bf(xa[3]);
    a[4] = f2bf(xb[0]); a[5] = f2bf(xb[1]); a[6] = f2bf(xb[2]); a[7] = f2bf(xb[3]);
#pragma unroll
    for (int nt = 0; nt < 8; ++nt) {
      s16x8 b = *(const s16x8*)(wbase + (size_t)nt * 16 * 256 + ks * 32);
      acc[nt] = mfma16(a, b, acc[nt]);
    }
  }
#pragma unroll
  for (int nt = 0; nt < 8; ++nt) {
#pragma unroll
    for (int r = 0; r < 4; ++r) {
      int col = col0 + nt * 16 + l16;
      int row = row0 + quad * 4 + r;
      float v = acc[nt][r];
      if (EPI == 0) {
        outb[(size_t)row * 256 + col] = f2bf(v);
      } else if (EPI == 1) {
        if (col < 256) {
          outb[(size_t)row * 256 + col] = f2bf(v);
        } else {
          int c2 = col - 256, hh = c2 >> 6, ch = c2 & 63;
          int grp = row >> kvshift, tok = row & ((1 << kvshift) - 1);
          outvT[((size_t)((grp * 4 + hh) * 64 + ch) << kvshift) + tok] = f2bf(v);
        }
      } else {
        outf[(size_t)row * 256 + col] = v + bias[col];
      }
    }
  }
}

// ---------------- flash attention: wave = (window, head, 16-row q-tile) ----------------
__global__ __launch_bounds__(256) void attn_k(const short* __restrict__ qbuf,
                                              const short* __restrict__ kbuf,
                                              const short* __restrict__ vT,
                                              float* __restrict__ wf, int kvlen) {
  __shared__ short Plds[4][16][72];
  const int w = threadIdx.x >> 6, lane = threadIdx.x & 63;
  const int l16 = lane & 15, quad = lane >> 4;
  const int gid = blockIdx.x * 4 + w;
  const int qt = gid & 3, h = (gid >> 2) & 3, win = gid >> 4;
  const int qrow0 = win * 64 + qt * 16;
  const int grp = (kvlen == 64) ? win : (win >= NWF ? 1 : 0);
  const size_t krow0 = (size_t)grp * kvlen;
  const short* vTb = vT + (size_t)(grp * 4 + h) * 64 * kvlen;
  const float C1 = 0.125f * 1.4426950408889634f;   // scale * log2(e)

  s16x8 aq[2];
#pragma unroll
  for (int ks = 0; ks < 2; ++ks)
    aq[ks] = *(const s16x8*)(qbuf + (size_t)(qrow0 + l16) * 256 + h * 64 + ks * 32 + quad * 8);

  f32x4 O[4], m2, li;
#pragma unroll
  for (int r = 0; r < 4; ++r) { m2[r] = -1e30f; li[r] = 0.f; }
#pragma unroll
  for (int nt = 0; nt < 4; ++nt)
#pragma unroll
    for (int r = 0; r < 4; ++r) O[nt][r] = 0.f;

  const int ntile = kvlen >> 6;
  for (int t = 0; t < ntile; ++t) {
    f32x4 S[4];
#pragma unroll
    for (int nt = 0; nt < 4; ++nt)
#pragma unroll
      for (int r = 0; r < 4; ++r) S[nt][r] = 0.f;
#pragma unroll
    for (int ks = 0; ks < 2; ++ks)
#pragma unroll
      for (int nt = 0; nt < 4; ++nt) {
        s16x8 bk = *(const s16x8*)(kbuf + (krow0 + t * 64 + nt * 16 + l16) * 256 + h * 64 + ks * 32 + quad * 8);
        S[nt] = mfma16(aq[ks], bk, S[nt]);
      }
    // softmax in log2 domain
    f32x4 mx;
#pragma unroll
    for (int r = 0; r < 4; ++r) {
      S[0][r] *= C1; S[1][r] *= C1; S[2][r] *= C1; S[3][r] *= C1;
      mx[r] = fmaxf(fmaxf(S[0][r], S[1][r]), fmaxf(S[2][r], S[3][r]));
    }
#pragma unroll
    for (int msk = 1; msk <= 8; msk <<= 1)
#pragma unroll
      for (int r = 0; r < 4; ++r) mx[r] = fmaxf(mx[r], __shfl_xor(mx[r], msk));
    f32x4 al, rs;
#pragma unroll
    for (int r = 0; r < 4; ++r) {
      float mn = fmaxf(m2[r], mx[r]);
      al[r] = __builtin_amdgcn_exp2f(m2[r] - mn);
      m2[r] = mn;
      rs[r] = 0.f;
    }
#pragma unroll
    for (int nt = 0; nt < 4; ++nt)
#pragma unroll
      for (int r = 0; r < 4; ++r) {
        float p = __builtin_amdgcn_exp2f(S[nt][r] - m2[r]);
        S[nt][r] = p;
        rs[r] += p;
        O[nt][r] *= al[r];
      }
#pragma unroll
    for (int msk = 1; msk <= 8; msk <<= 1)
#pragma unroll
      for (int r = 0; r < 4; ++r) rs[r] += __shfl_xor(rs[r], msk);
#pragma unroll
    for (int r = 0; r < 4; ++r) li[r] = li[r] * al[r] + rs[r];

    // P: C/D layout -> LDS -> A layout (per-wave region)
#pragma unroll
    for (int nt = 0; nt < 4; ++nt)
#pragma unroll
      for (int r = 0; r < 4; ++r)
        Plds[w][quad * 4 + r][nt * 16 + l16] = f2bf(S[nt][r]);
    __syncthreads();
#pragma unroll
    for (int ks2 = 0; ks2 < 2; ++ks2) {
      s16x8 ap = *(const s16x8*)&Plds[w][l16][ks2 * 32 + quad * 8];
#pragma unroll
      for (int nt = 0; nt < 4; ++nt) {
        s16x8 bv = *(const s16x8*)(vTb + (size_t)(nt * 16 + l16) * kvlen + t * 64 + ks2 * 32 + quad * 8);
        O[nt] = mfma16(ap, bv, O[nt]);
      }
    }
    __syncthreads();
  }
  f32x4 inv;
#pragma unroll
  for (int r = 0; r < 4; ++r) inv[r] = 1.f / li[r];
#pragma unroll
  for (int nt = 0; nt < 4; ++nt)
#pragma unroll
    for (int r = 0; r < 4; ++r) {
      size_t oi = (size_t)(qrow0 + quad * 4 + r) * 256 + h * 64 + nt * 16 + l16;
      wf[oi] += O[nt][r] * inv[r];
    }
}

// ---------------- scatter-add projected windows into out (LDS transpose) ----------------
__global__ __launch_bounds__(256) void scatter_k(const float* __restrict__ proj,
                                                 const int* __restrict__ selidx,
                                                 float* __restrict__ out) {
  __shared__ float tile[64][33];
  int slot = blockIdx.x;
  int b = slot >= NWF;
  int w = selidx[slot];
  int y0 = (w >> 5) * 8, x0 = (w & 31) * 8;
  int tid = threadIdx.x;
  int cc2 = tid & 31, t4 = tid >> 5;                    // coalesced proj read
  int j = tid & 7, i = (tid >> 3) & 7, c4 = tid >> 6;   // out RMW mapping
  for (int c0 = 0; c0 < 256; c0 += 32) {
    for (int ts = 0; ts < 8; ++ts) {
      int tok = ts * 8 + t4;
      tile[tok][cc2] = proj[(size_t)(slot * 64 + tok) * 256 + c0 + cc2];
    }
    __syncthreads();
    for (int cs = 0; cs < 8; ++cs) {
      int c = c0 + cs * 4 + c4;
      size_t oidx = ((size_t)(b * 256 + c) * 256 + y0 + i) * 256 + x0 + j;
      out[oidx] += tile[i * 8 + j][cs * 4 + c4];
    }
    __syncthreads();
  }
}

extern "C" void kernel_launch(void* const* d_in, const int* in_sizes, int n_in,
                              void* d_out, int out_size, void* d_ws, size_t ws_size,
                              hipStream_t stream) {
  const float* fm    = (const float*)d_in[0];
  const float* unc   = (const float*)d_in[1];
  const float* srw   = (const float*)d_in[2];
  const float* srb   = (const float*)d_in[3];
  const float* lng   = (const float*)d_in[4];
  const float* lnb   = (const float*)d_in[5];
  const float* wq_l  = (const float*)d_in[6];
  const float* wkv_l = (const float*)d_in[7];
  const float* wq_g  = (const float*)d_in[8];
  const float* wkv_g = (const float*)d_in[9];
  const float* wpm   = (const float*)d_in[10];
  const float* bp    = (const float*)d_in[11];
  float* out = (float*)d_out;

  char* ws = (char*)d_ws;
  size_t off = 0;
  auto alloc = [&](size_t bytes) -> char* {
    char* p = ws + off;
    off += (bytes + 255) & ~(size_t)255;
    return p;
  };
  float* wf     = (float*)alloc((size_t)MROWS * 256 * 4);
  short* qbuf   = (short*)alloc((size_t)MROWS * 256 * 2);
  short* kbufl  = (short*)alloc((size_t)MROWS * 256 * 2);   // contiguous with qbuf
  short* vTl    = (short*)alloc((size_t)MROWS * 256 * 2);
  short* kbufg  = (short*)alloc((size_t)2048 * 256 * 2);
  short* vTg    = (short*)alloc((size_t)2048 * 256 * 2);
  float* g      = (float*)alloc((size_t)2048 * 256 * 4);
  float* scores = (float*)alloc(2048 * 4);
  int*   selidx = (int*)alloc(NWTOT * 4);
  short* wtql   = (short*)alloc(256 * 256 * 2);
  short* wtkvl  = (short*)alloc(512 * 256 * 2);
  short* wtqg   = (short*)alloc(256 * 256 * 2);
  short* wtkvg  = (short*)alloc(512 * 256 * 2);
  short* wtp    = (short*)alloc(256 * 256 * 2);
  float* proj   = (float*)qbuf;   // aliases qbuf+kbufl (both dead by projection time)

  // weights -> bf16 transposed
  wtrans_k<<<256, 256, 0, stream>>>(wq_l, wtql, 256);
  wtrans_k<<<512, 256, 0, stream>>>(wkv_l, wtkvl, 512);
  wtrans_k<<<256, 256, 0, stream>>>(wq_g, wtqg, 256);
  wtrans_k<<<512, 256, 0, stream>>>(wkv_g, wtkvg, 512);
  wtrans_k<<<256, 256, 0, stream>>>(wpm, wtp, 256);

  // selection
  score_k<<<2048, 64, 0, stream>>>(unc, scores);
  topk_k<<<2, 1024, 0, stream>>>(scores, selidx);
  gather_k<<<NWTOT, 256, 0, stream>>>(fm, selidx, wf);

  // fused identity-copy + global branch (conv + LN + GELU)
  convcopy_k<<<512, 256, 0, stream>>>(fm, srw, srb, lng, lnb, g, out);

  // local window attention
  gemm_k<0><<<dim3(NWTOT, 2), 256, 0, stream>>>(wf, wtql, nullptr, qbuf, nullptr, nullptr, 0);
  gemm_k<1><<<dim3(NWTOT, 4), 256, 0, stream>>>(wf, wtkvl, nullptr, kbufl, vTl, nullptr, 6);
  attn_k<<<NWTOT * 4, 256, 0, stream>>>(qbuf, kbufl, vTl, wf, 64);

  // global cross attention
  gemm_k<0><<<dim3(NWTOT, 2), 256, 0, stream>>>(wf, wtqg, nullptr, qbuf, nullptr, nullptr, 0);
  gemm_k<1><<<dim3(32, 4), 256, 0, stream>>>(g, wtkvg, nullptr, kbufg, vTg, nullptr, 10);
  attn_k<<<NWTOT * 4, 256, 0, stream>>>(qbuf, kbufg, vTg, wf, 1024);

  // projection + scatter-add
  gemm_k<2><<<dim3(NWTOT, 2), 256, 0, stream>>>(wf, wtp, bp, nullptr, nullptr, proj, 0);
  scatter_k<<<NWTOT, 256, 0, stream>>>(proj, selidx, out);
}